// Round 1
// baseline (24443.047 us; speedup 1.0000x reference)
//
#include <hip/hip_runtime.h>
#include <math.h>

#define H 32
#define NTHR 256

// softplus(beta=20): h = log(1+exp(20z))/20, s = d/dz = sigmoid(20z)
// stable: h = max(z,0) + log1p(exp(-|20z|))/20
__device__ __forceinline__ void act(float z, float& h, float& s) {
    float bz = 20.0f * z;
    float e = __expf(-fabsf(bz));                 // (0,1]
    float r = __builtin_amdgcn_rcpf(1.0f + e);    // 1/(1+e), ~1ulp
    s = (bz >= 0.0f) ? r : (1.0f - r);            // sigmoid(20z)
    h = fmaxf(z, 0.0f) + 0.05f * __logf(1.0f + e);
}

__device__ __forceinline__ float sigmoid20(float z) {
    float bz = 20.0f * z;
    float e = __expf(-fabsf(bz));
    float r = __builtin_amdgcn_rcpf(1.0f + e);
    return (bz >= 0.0f) ? r : (1.0f - r);
}

__global__ void __launch_bounds__(NTHR)
presdiv_kernel(const float* __restrict__ x,
               const float* __restrict__ gW1, const float* __restrict__ gb1,
               const float* __restrict__ gW2, const float* __restrict__ gb2,
               const float* __restrict__ gW3, const float* __restrict__ gb3,
               const float* __restrict__ gW4,
               float* __restrict__ out, int N)
{
    __shared__ __align__(16) float sW1[3 * H];
    __shared__ __align__(16) float sW2[H * H];
    __shared__ __align__(16) float sW3[H * H];
    __shared__ __align__(16) float sW4[H * 3];
    __shared__ __align__(16) float sB1[H];
    __shared__ __align__(16) float sB2[H];
    __shared__ __align__(16) float sB3[H];

    const int tid = threadIdx.x;
    for (int i = tid; i < H * H; i += NTHR) { sW2[i] = gW2[i]; sW3[i] = gW3[i]; }
    if (tid < 3 * H) { sW1[tid] = gW1[tid]; sW4[tid] = gW4[tid]; }
    if (tid < H)     { sB1[tid] = gb1[tid]; sB2[tid] = gb2[tid]; sB3[tid] = gb3[tid]; }
    __syncthreads();

    const int n = blockIdx.x * NTHR + tid;
    if (n >= N) return;

    const float x0 = x[3 * n + 0];
    const float x1 = x[3 * n + 1];
    const float x2 = x[3 * n + 2];

    float s1[H], s2[H], s3[H];

    // ---- forward layer 1 ----
    float h1[H];
    #pragma unroll
    for (int j = 0; j < H; ++j) {
        float z = sB1[j];
        z = fmaf(x0, sW1[0 * H + j], z);
        z = fmaf(x1, sW1[1 * H + j], z);
        z = fmaf(x2, sW1[2 * H + j], z);
        act(z, h1[j], s1[j]);
    }

    // ---- forward layer 2 ----
    float h2[H];
    #pragma unroll
    for (int j = 0; j < H; ++j) h2[j] = sB2[j];
    #pragma unroll
    for (int k = 0; k < H; ++k) {
        const float a = h1[k];
        #pragma unroll
        for (int j = 0; j < H; ++j) h2[j] = fmaf(a, sW2[k * H + j], h2[j]);
    }
    #pragma unroll
    for (int j = 0; j < H; ++j) { float hh, ss; act(h2[j], hh, ss); h2[j] = hh; s2[j] = ss; }

    // ---- forward layer 3: only s3 needed (h3/layer-4 forward never used) ----
    {
        float z3[H];
        #pragma unroll
        for (int j = 0; j < H; ++j) z3[j] = sB3[j];
        #pragma unroll
        for (int k = 0; k < H; ++k) {
            const float a = h2[k];
            #pragma unroll
            for (int j = 0; j < H; ++j) z3[j] = fmaf(a, sW3[k * H + j], z3[j]);
        }
        #pragma unroll
        for (int j = 0; j < H; ++j) s3[j] = sigmoid20(z3[j]);
    }

    // ---- 3 JVP passes (direction loop kept rolled to cap register pressure) ----
    float o0 = 0.f, o1 = 0.f, o2 = 0.f;
    #pragma unroll 1
    for (int i = 0; i < 3; ++i) {
        float t[H], u[H];
        // tangent through layer 1: dz1/dx_i = W1[i,:]
        #pragma unroll
        for (int j = 0; j < H; ++j) t[j] = s1[j] * sW1[i * H + j];

        // layer 2
        #pragma unroll
        for (int j = 0; j < H; ++j) u[j] = 0.f;
        #pragma unroll
        for (int k = 0; k < H; ++k) {
            const float a = t[k];
            #pragma unroll
            for (int j = 0; j < H; ++j) u[j] = fmaf(a, sW2[k * H + j], u[j]);
        }
        #pragma unroll
        for (int j = 0; j < H; ++j) t[j] = s2[j] * u[j];

        // layer 3
        #pragma unroll
        for (int j = 0; j < H; ++j) u[j] = 0.f;
        #pragma unroll
        for (int k = 0; k < H; ++k) {
            const float a = t[k];
            #pragma unroll
            for (int j = 0; j < H; ++j) u[j] = fmaf(a, sW3[k * H + j], u[j]);
        }

        // layer 4 rows: J[k,i] = sum_j (s3*u)[j] * W4[j,k]
        float J0 = 0.f, J1 = 0.f, J2 = 0.f;
        #pragma unroll
        for (int j = 0; j < H; ++j) {
            const float tt = s3[j] * u[j];
            J0 = fmaf(tt, sW4[3 * j + 0], J0);
            J1 = fmaf(tt, sW4[3 * j + 1], J1);
            J2 = fmaf(tt, sW4[3 * j + 2], J2);
        }
        // out0 = J01 + J12; out1 = -J00 + J22; out2 = -J10 - J21
        if (i == 0)      { o1 -= J0; o2 -= J1; }
        else if (i == 1) { o0 += J0; o2 -= J2; }
        else             { o0 += J1; o1 += J2; }
    }

    out[3 * n + 0] = o0;
    out[3 * n + 1] = o1;
    out[3 * n + 2] = o2;
}

extern "C" void kernel_launch(void* const* d_in, const int* in_sizes, int n_in,
                              void* d_out, int out_size, void* d_ws, size_t ws_size,
                              hipStream_t stream)
{
    const float* x  = (const float*)d_in[0];
    const float* W1 = (const float*)d_in[1];
    const float* b1 = (const float*)d_in[2];
    const float* W2 = (const float*)d_in[3];
    const float* b2 = (const float*)d_in[4];
    const float* W3 = (const float*)d_in[5];
    const float* b3 = (const float*)d_in[6];
    const float* W4 = (const float*)d_in[7];
    // d_in[8] = b4 is unused: it cancels in the Jacobian.
    float* out = (float*)d_out;

    const int N = in_sizes[0] / 3;
    const int blocks = (N + NTHR - 1) / NTHR;
    presdiv_kernel<<<blocks, NTHR, 0, stream>>>(x, W1, b1, W2, b2, W3, b3, W4, out, N);
}

// Round 2
// 756.442 us; speedup vs baseline: 32.3132x; 32.3132x over previous
//
#include <hip/hip_runtime.h>
#include <math.h>

#define H 32
#define NTHR 256

// softplus(beta=20): h = max(z,0) + log1p(exp(-|20z|))/20 ; s = sigmoid(20z)
__device__ __forceinline__ float act_hs(float z, float& s) {
    float bz = 20.0f * z;
    float e = __expf(-fabsf(bz));                 // (0,1]
    float r = __builtin_amdgcn_rcpf(1.0f + e);    // ~1ulp
    s = (bz >= 0.0f) ? r : (1.0f - r);
    return fmaxf(z, 0.0f) + 0.05f * __logf(1.0f + e);
}

__device__ __forceinline__ float sigmoid20(float z) {
    float bz = 20.0f * z;
    float e = __expf(-fabsf(bz));
    float r = __builtin_amdgcn_rcpf(1.0f + e);
    return (bz >= 0.0f) ? r : (1.0f - r);
}

__global__ void __launch_bounds__(NTHR)
presdiv_kernel(const float* __restrict__ x,
               const float* __restrict__ W1, const float* __restrict__ b1,
               const float* __restrict__ W2, const float* __restrict__ b2,
               const float* __restrict__ W3, const float* __restrict__ b3,
               const float* __restrict__ W4,
               float* __restrict__ out, int N)
{
    // Clamp instead of early-return: keeps control flow uniform so the
    // compiler can scalarize the (wave-uniform) weight loads into s_load.
    int n = blockIdx.x * NTHR + threadIdx.x;
    n = (n < N) ? n : (N - 1);

    const float x0 = x[3 * n + 0];
    const float x1 = x[3 * n + 1];
    const float x2 = x[3 * n + 2];

    float o0 = 0.f, o1 = 0.f, o2 = 0.f;

    // Recompute the forward pass inside each direction pass: peak live state
    // is h[32]+t[32]+u[32] = 96 floats (vs ~224 when caching s1/s2/s3, which
    // spilled: R1 showed VGPR=256 + 36 GB scratch traffic).
    #pragma unroll 1
    for (int i = 0; i < 3; ++i) {
        float h[H], t[H], u[H];

        // ---- layer 1: forward + tangent seed (dz1/dx_i = W1[i,:]) ----
        #pragma unroll
        for (int j = 0; j < H; ++j) {
            float z = b1[j];
            z = fmaf(x0, W1[0 * H + j], z);
            z = fmaf(x1, W1[1 * H + j], z);
            z = fmaf(x2, W1[2 * H + j], z);
            float s;
            h[j] = act_hs(z, s);
            t[j] = s * W1[i * H + j];
        }

        // ---- layer 2 ----
        // tangent GEMV first (uses t; t dies after)
        #pragma unroll
        for (int j = 0; j < H; ++j) u[j] = 0.f;
        #pragma unroll
        for (int k = 0; k < H; ++k) {
            const float a = t[k];
            #pragma unroll
            for (int j = 0; j < H; ++j) u[j] = fmaf(a, W2[k * H + j], u[j]);
        }
        // forward GEMV into t (reuse; uses h; h dies after)
        #pragma unroll
        for (int j = 0; j < H; ++j) t[j] = b2[j];
        #pragma unroll
        for (int k = 0; k < H; ++k) {
            const float a = h[k];
            #pragma unroll
            for (int j = 0; j < H; ++j) t[j] = fmaf(a, W2[k * H + j], t[j]);
        }
        // activation: h = softplus(z2), t = s2 * u
        #pragma unroll
        for (int j = 0; j < H; ++j) {
            float s;
            h[j] = act_hs(t[j], s);
            t[j] = s * u[j];
        }

        // ---- layer 3 ----
        #pragma unroll
        for (int j = 0; j < H; ++j) u[j] = 0.f;
        #pragma unroll
        for (int k = 0; k < H; ++k) {
            const float a = t[k];
            #pragma unroll
            for (int j = 0; j < H; ++j) u[j] = fmaf(a, W3[k * H + j], u[j]);
        }
        #pragma unroll
        for (int j = 0; j < H; ++j) t[j] = b3[j];
        #pragma unroll
        for (int k = 0; k < H; ++k) {
            const float a = h[k];
            #pragma unroll
            for (int j = 0; j < H; ++j) t[j] = fmaf(a, W3[k * H + j], t[j]);
        }

        // ---- layer 4 rows: J_k = sum_j sigmoid(20*z3[j]) * u[j] * W4[j,k] ----
        float J0 = 0.f, J1 = 0.f, J2 = 0.f;
        #pragma unroll
        for (int j = 0; j < H; ++j) {
            const float tt = sigmoid20(t[j]) * u[j];
            J0 = fmaf(tt, W4[3 * j + 0], J0);
            J1 = fmaf(tt, W4[3 * j + 1], J1);
            J2 = fmaf(tt, W4[3 * j + 2], J2);
        }
        // out0 = J01 + J12; out1 = -J00 + J22; out2 = -J10 - J21
        if (i == 0)      { o1 -= J0; o2 -= J1; }
        else if (i == 1) { o0 += J0; o2 -= J2; }
        else             { o0 += J1; o1 += J2; }
    }

    out[3 * n + 0] = o0;
    out[3 * n + 1] = o1;
    out[3 * n + 2] = o2;
}

extern "C" void kernel_launch(void* const* d_in, const int* in_sizes, int n_in,
                              void* d_out, int out_size, void* d_ws, size_t ws_size,
                              hipStream_t stream)
{
    const float* x  = (const float*)d_in[0];
    const float* W1 = (const float*)d_in[1];
    const float* b1 = (const float*)d_in[2];
    const float* W2 = (const float*)d_in[3];
    const float* b2 = (const float*)d_in[4];
    const float* W3 = (const float*)d_in[5];
    const float* b3 = (const float*)d_in[6];
    const float* W4 = (const float*)d_in[7];
    // d_in[8] = b4 unused: constant offset cancels in the Jacobian.
    float* out = (float*)d_out;

    const int N = in_sizes[0] / 3;
    const int blocks = (N + NTHR - 1) / NTHR;
    presdiv_kernel<<<blocks, NTHR, 0, stream>>>(x, W1, b1, W2, b2, W3, b3, W4, out, N);
}